// Round 12
// baseline (58.785 us; speedup 1.0000x reference)
//
#include <hip/hip_runtime.h>

#define IND 256
#define KC  32

__global__ __launch_bounds__(64, 2)
void FeatureEncodingLayer_30374008718005_kernel(
        const float* __restrict__ X,      // [1024][256]
        const float* __restrict__ W,      // [4096][256]
        const float* __restrict__ bias,   // [4096]
        float* __restrict__ outf)         // [1024][4][4][2048] float32 = Re(kron)
{
    // k-major tiles; storage col = logical ^ ((k>>2)<<3). Staging writes hit 64
    // distinct cols (2-way banks, free); reads are 8-lane broadcasts, 2-way max.
    __shared__ float Xs[KC][64];   // Xs[k][b_local]
    __shared__ float Ws[KC][64];   // Ws[k][u_local]

    const int tid = threadIdx.x;   // 64 threads = 1 wave
    const int tx  = tid & 7;       // owns units 8tx..8tx+7  (pairs 4tx..4tx+3)
    const int ty  = tid >> 3;      // owns batches 8ty..8ty+7

    const int kq  = tid & 7;       // staging: float4 k-column (k = 4kq..4kq+3)
    const int rr  = tid >> 3;      // staging: row subgroup 0..7
    const int sw  = kq << 3;       // staging write swizzle

    const int pt = blockIdx.x & 63;   // pair tile (32 pairs)
    const int bt = blockIdx.x >> 6;   // batch tile (64 batches)
    const int b0 = bt * 64;
    const int p0 = pt * 32;
    const int u0 = p0 * 2;            // 64 units

    float acc[8][8];
#pragma unroll
    for (int i = 0; i < 8; ++i)
#pragma unroll
        for (int j = 0; j < 8; ++j) acc[i][j] = 0.f;

    for (int c = 0; c < IND / KC; ++c) {
        if (c) __syncthreads();   // 1-wave block: compiles to a cheap wait+barrier

        // ---- stage X chunk: 64 b x 32 k (8 float4 loads, then transpose-write) ----
        float4 vx[8];
#pragma unroll
        for (int j = 0; j < 8; ++j) {
            const int r = rr + 8 * j;
            vx[j] = *reinterpret_cast<const float4*>(
                X + (size_t)(b0 + r) * IND + c * KC + kq * 4);
        }
#pragma unroll
        for (int j = 0; j < 8; ++j) {
            const int col = (rr + 8 * j) ^ sw;
            Xs[kq * 4 + 0][col] = vx[j].x;
            Xs[kq * 4 + 1][col] = vx[j].y;
            Xs[kq * 4 + 2][col] = vx[j].z;
            Xs[kq * 4 + 3][col] = vx[j].w;
        }
        // ---- stage W chunk: 64 u x 32 k ----
        float4 vw[8];
#pragma unroll
        for (int j = 0; j < 8; ++j) {
            const int u = rr + 8 * j;
            vw[j] = *reinterpret_cast<const float4*>(
                W + (size_t)(u0 + u) * IND + c * KC + kq * 4);
        }
#pragma unroll
        for (int j = 0; j < 8; ++j) {
            const int col = (rr + 8 * j) ^ sw;
            Ws[kq * 4 + 0][col] = vw[j].x;
            Ws[kq * 4 + 1][col] = vw[j].y;
            Ws[kq * 4 + 2][col] = vw[j].z;
            Ws[kq * 4 + 3][col] = vw[j].w;
        }
        __syncthreads();

        // ---- compute: 4x ds_read_b128 + 64 FMA per k ----
#pragma unroll 4
        for (int k = 0; k < KC; ++k) {
            const int g  = (k >> 2) << 3;
            const int xc = (ty * 8) ^ g;
            const int wc = (tx * 8) ^ g;
            const float4 x0 = *reinterpret_cast<const float4*>(&Xs[k][xc]);
            const float4 x1 = *reinterpret_cast<const float4*>(&Xs[k][xc + 4]);
            const float4 w0 = *reinterpret_cast<const float4*>(&Ws[k][wc]);
            const float4 w1 = *reinterpret_cast<const float4*>(&Ws[k][wc + 4]);
            const float xr[8] = {x0.x, x0.y, x0.z, x0.w, x1.x, x1.y, x1.z, x1.w};
            const float wv[8] = {w0.x, w0.y, w0.z, w0.w, w1.x, w1.y, w1.z, w1.w};
#pragma unroll
            for (int i = 0; i < 8; ++i)
#pragma unroll
                for (int j = 0; j < 8; ++j)
                    acc[i][j] = fmaf(xr[i], wv[j], acc[i][j]);
        }
    }

    // ---- epilogue: bias + fast trig + Re(Ra x Rb) + coalesced float4 stores ----
    const float4 bva = *reinterpret_cast<const float4*>(bias + u0 + tx * 8);
    const float4 bvb = *reinterpret_cast<const float4*>(bias + u0 + tx * 8 + 4);
    const float bv[8] = {bva.x, bva.y, bva.z, bva.w, bvb.x, bvb.y, bvb.z, bvb.w};

#pragma unroll
    for (int rb = 0; rb < 8; ++rb) {
        const int b = b0 + ty * 8 + rb;
        float ca[4], sa[4], cb[4], sb[4], oo[4];
#pragma unroll
        for (int rp = 0; rp < 4; ++rp) {
            const float tA = acc[rb][2 * rp]     + bv[2 * rp];
            const float tB = acc[rb][2 * rp + 1] + bv[2 * rp + 1];
            float sA, cA, sB, cB;
            __sincosf(tA, &sA, &cA);
            __sincosf(tB, &sB, &cB);
            ca[rp] = 0.5f * (1.f + cA);            // cos^2(tA/2)
            sa[rp] = 0.5f * (1.f - cA);            // sin^2(tA/2)
            cb[rp] = 0.5f * (1.f + cB);
            sb[rp] = 0.5f * (1.f - cB);
            oo[rp] = 0.25f * sA * sB;              // sin(tA)/2 * sin(tB)/2
        }
        // float index = (b*16 + rc)*2048 + p0 + 4*tx
        float* bp = outf + (size_t)b * 32768 + p0 + tx * 4;

#define STORE4(rc, EXPR) do {                                   \
        float4 v_;                                              \
        { const int rp = 0; v_.x = (EXPR); }                    \
        { const int rp = 1; v_.y = (EXPR); }                    \
        { const int rp = 2; v_.z = (EXPR); }                    \
        { const int rp = 3; v_.w = (EXPR); }                    \
        *reinterpret_cast<float4*>(bp + (rc) * 2048) = v_;      \
    } while (0)

        STORE4(0,  ca[rp] * cb[rp]);
        STORE4(1,  0.f);
        STORE4(2,  0.f);
        STORE4(3,  -oo[rp]);
        STORE4(4,  0.f);
        STORE4(5,  ca[rp] * sb[rp]);
        STORE4(6,  oo[rp]);
        STORE4(7,  0.f);
        STORE4(8,  0.f);
        STORE4(9,  oo[rp]);
        STORE4(10, sa[rp] * cb[rp]);
        STORE4(11, 0.f);
        STORE4(12, -oo[rp]);
        STORE4(13, 0.f);
        STORE4(14, 0.f);
        STORE4(15, sa[rp] * sb[rp]);
#undef STORE4
    }
}

extern "C" void kernel_launch(void* const* d_in, const int* in_sizes, int n_in,
                              void* d_out, int out_size, void* d_ws, size_t ws_size,
                              hipStream_t stream) {
    const float* X  = (const float*)d_in[0];
    const float* W  = (const float*)d_in[1];
    const float* bv = (const float*)d_in[2];

    // 16 batch-tiles x 64 pair-tiles = 1024 one-wave blocks (~4 per CU)
    FeatureEncodingLayer_30374008718005_kernel<<<dim3(1024), dim3(64), 0, stream>>>(
        X, W, bv, (float*)d_out);
}

// Round 13
// 49.748 us; speedup vs baseline: 1.1817x; 1.1817x over previous
//
#include <hip/hip_runtime.h>

#define IND 256
#define KC  32

__global__ __launch_bounds__(256, 2)
void FeatureEncodingLayer_30374008718005_kernel(
        const float* __restrict__ X,      // [1024][256]
        const float* __restrict__ W,      // [4096][256]
        const float* __restrict__ bias,   // [4096]
        float* __restrict__ outf)         // [1024][4][4][2048] float32 = Re(kron)
{
    // W tile only; X never touches LDS (wave-uniform scalar loads).
    // storage col = u ^ ((k>>2)<<3): staging writes 2-way banks, reads linear-permuted.
    __shared__ float Ws[KC][256];

    const int tid  = threadIdx.x;
    const int lane = tid & 63;
    const int wid  = __builtin_amdgcn_readfirstlane(tid >> 6);  // wave 0..3

    const int ut = blockIdx.x & 15;    // unit tile: 256 units (128 pairs)
    const int bt = blockIdx.x >> 4;    // batch tile: 32 batches
    const int b0 = bt * 32;
    const int u0 = ut * 256;
    const int p0 = ut * 128;

    // staging roles: 256 threads cover 256 units x 32 k per chunk
    const int rq = tid >> 3;   // unit subgroup 0..31
    const int q  = tid & 7;    // k-quad 0..7 (k = 4q..4q+3)

    // wave-uniform X base: this wave's 8 batches are b0+8*wid .. +7
    const float* xw = X + (size_t)(b0 + 8 * wid) * IND;

    float acc[8][4];
#pragma unroll
    for (int i = 0; i < 8; ++i)
#pragma unroll
        for (int j = 0; j < 4; ++j) acc[i][j] = 0.f;

    for (int c = 0; c < IND / KC; ++c) {
        if (c) __syncthreads();
        // ---- stage W chunk: 256 u x 32 k, coalesced float4, transpose+swizzle ----
#pragma unroll
        for (int j = 0; j < 8; ++j) {
            const int u = rq + 32 * j;
            const float4 v = *reinterpret_cast<const float4*>(
                W + (size_t)(u0 + u) * IND + c * KC + q * 4);
            const int col = u ^ (q << 3);       // (k>>2) == q for k = 4q+i
            Ws[q * 4 + 0][col] = v.x;
            Ws[q * 4 + 1][col] = v.y;
            Ws[q * 4 + 2][col] = v.z;
            Ws[q * 4 + 3][col] = v.w;
        }
        __syncthreads();

        const float* xc = xw + c * KC;          // wave-uniform
        // ---- compute: 1x ds_read_b128 + 32 FMA per k ----
#pragma unroll 8
        for (int k = 0; k < KC; ++k) {
            const int s = ((k >> 2) & 7) << 3;
            const float4 wv = *reinterpret_cast<const float4*>(
                &Ws[k][(lane * 4) ^ s]);
#pragma unroll
            for (int i = 0; i < 8; ++i) {
                const float xv = xc[i * IND + k];   // uniform -> s_load (SMEM pipe)
                acc[i][0] = fmaf(xv, wv.x, acc[i][0]);
                acc[i][1] = fmaf(xv, wv.y, acc[i][1]);
                acc[i][2] = fmaf(xv, wv.z, acc[i][2]);
                acc[i][3] = fmaf(xv, wv.w, acc[i][3]);
            }
        }
    }

    // ---- epilogue: lane owns units u0+4L..+3 = pairs p0+2L, p0+2L+1 ----
    const float4 bv = *reinterpret_cast<const float4*>(bias + u0 + 4 * lane);

#pragma unroll
    for (int i = 0; i < 8; ++i) {
        const int b = b0 + 8 * wid + i;
        // pair 0: thetas from units 4L+0 (A), 4L+1 (B); pair 1: 4L+2, 4L+3
        float ca[2], sa[2], cb[2], sb[2], oo[2];
#pragma unroll
        for (int rp = 0; rp < 2; ++rp) {
            const float tA = acc[i][2 * rp]     + ((rp == 0) ? bv.x : bv.z);
            const float tB = acc[i][2 * rp + 1] + ((rp == 0) ? bv.y : bv.w);
            float sA, cA, sB, cB;
            __sincosf(tA, &sA, &cA);
            __sincosf(tB, &sB, &cB);
            ca[rp] = 0.5f * (1.f + cA);   // cos^2(tA/2)
            sa[rp] = 0.5f * (1.f - cA);   // sin^2(tA/2)
            cb[rp] = 0.5f * (1.f + cB);
            sb[rp] = 0.5f * (1.f - cB);
            oo[rp] = 0.25f * sA * sB;     // sin(tA)/2 * sin(tB)/2
        }
        float* bp = outf + (size_t)b * 32768 + p0 + 2 * lane;

#define STORE2(rc, EXPR) do {                                   \
        float2 v_;                                              \
        { const int rp = 0; v_.x = (EXPR); }                    \
        { const int rp = 1; v_.y = (EXPR); }                    \
        *reinterpret_cast<float2*>(bp + (rc) * 2048) = v_;      \
    } while (0)

        STORE2(0,  ca[rp] * cb[rp]);
        STORE2(1,  0.f);
        STORE2(2,  0.f);
        STORE2(3,  -oo[rp]);
        STORE2(4,  0.f);
        STORE2(5,  ca[rp] * sb[rp]);
        STORE2(6,  oo[rp]);
        STORE2(7,  0.f);
        STORE2(8,  0.f);
        STORE2(9,  oo[rp]);
        STORE2(10, sa[rp] * cb[rp]);
        STORE2(11, 0.f);
        STORE2(12, -oo[rp]);
        STORE2(13, 0.f);
        STORE2(14, 0.f);
        STORE2(15, sa[rp] * sb[rp]);
#undef STORE2
    }
}

extern "C" void kernel_launch(void* const* d_in, const int* in_sizes, int n_in,
                              void* d_out, int out_size, void* d_ws, size_t ws_size,
                              hipStream_t stream) {
    const float* X  = (const float*)d_in[0];
    const float* W  = (const float*)d_in[1];
    const float* bv = (const float*)d_in[2];

    // 32 batch-tiles x 16 unit-tiles = 512 blocks, 256 threads (4 waves)
    FeatureEncodingLayer_30374008718005_kernel<<<dim3(512), dim3(256), 0, stream>>>(
        X, W, bv, (float*)d_out);
}

// Round 14
// 44.595 us; speedup vs baseline: 1.3182x; 1.1155x over previous
//
#include <hip/hip_runtime.h>

#define IND 256
#define KC  32

__global__ __launch_bounds__(256, 4)
void FeatureEncodingLayer_30374008718005_kernel(
        const float* __restrict__ X,      // [1024][256]
        const float* __restrict__ W,      // [4096][256]
        const float* __restrict__ bias,   // [4096]
        float* __restrict__ outf)         // [1024][4][4][2048] float32 = Re(kron)
{
    // Double-buffered W tile, k-major, XOR-swizzled: col = u ^ ((k>>2)<<2).
    // Compute read: all 64 lanes read one full row (bijective) -> conflict-free.
    // Staging write: banks 2-way max (free). X never touches LDS (scalar loads).
    __shared__ float Ws[2][KC][128];

    const int tid  = threadIdx.x;
    const int lane = tid & 63;
    const int wid  = __builtin_amdgcn_readfirstlane(tid >> 6);  // wave 0..3

    const int ut = blockIdx.x & 31;    // 32 unit tiles x 128 units
    const int bt = blockIdx.x >> 5;    // 32 batch tiles x 32 batches
    const int b0 = bt * 32;
    const int u0 = ut * 128;
    const int p0 = ut * 64;

    // staging roles: 128 u x 32 k per chunk; lanes 0..7 cover one row's 128B
    const int q  = tid & 7;    // k-quad (k = 4q..4q+3)
    const int rq = tid >> 3;   // row subgroup 0..31  (rows u = rq + 32j)

    // wave-uniform X base: this wave's 8 batches
    const float* xw = X + (size_t)(b0 + 8 * wid) * IND;

    float acc[8][2];
#pragma unroll
    for (int i = 0; i < 8; ++i) { acc[i][0] = 0.f; acc[i][1] = 0.f; }

    float4 pf[4];
#define STAGE_LOAD(c) do {                                                     \
    _Pragma("unroll")                                                          \
    for (int j = 0; j < 4; ++j)                                                \
        pf[j] = *reinterpret_cast<const float4*>(                              \
            W + (size_t)(u0 + rq + 32 * j) * IND + (c) * KC + q * 4);          \
    } while (0)

#define STAGE_WRITE(buf) do {                                                  \
    _Pragma("unroll")                                                          \
    for (int j = 0; j < 4; ++j) {                                              \
        const int col = (rq + 32 * j) ^ (q << 2);                              \
        Ws[buf][q * 4 + 0][col] = pf[j].x;                                     \
        Ws[buf][q * 4 + 1][col] = pf[j].y;                                     \
        Ws[buf][q * 4 + 2][col] = pf[j].z;                                     \
        Ws[buf][q * 4 + 3][col] = pf[j].w;                                     \
    }                                                                          \
    } while (0)

    STAGE_LOAD(0);
    STAGE_WRITE(0);
    __syncthreads();

    for (int c = 0; c < IND / KC; ++c) {
        const int cur = c & 1;
        if (c < IND / KC - 1) STAGE_LOAD(c + 1);   // prefetch: no wait, hidden by compute

        const float* xc = xw + c * KC;             // wave-uniform -> scalar loads
#pragma unroll 4
        for (int k = 0; k < KC; ++k) {
            const int s = ((k >> 2) & 7) << 2;
            const float2 wv = *reinterpret_cast<const float2*>(
                &Ws[cur][k][(2 * lane) ^ s]);      // ds_read_b64, conflict-free
#pragma unroll
            for (int i = 0; i < 8; ++i) {
                const float xv = xc[i * IND + k];
                acc[i][0] = fmaf(xv, wv.x, acc[i][0]);
                acc[i][1] = fmaf(xv, wv.y, acc[i][1]);
            }
        }
        if (c < IND / KC - 1) {
            STAGE_WRITE(cur ^ 1);                  // waits only its own loads
            __syncthreads();                       // one barrier per chunk
        }
    }
#undef STAGE_LOAD
#undef STAGE_WRITE

    // ---- epilogue: lane owns pair p0+lane (units u0+2*lane, +1), 8 batches ----
    const float2 bv = *reinterpret_cast<const float2*>(bias + u0 + 2 * lane);

#pragma unroll
    for (int i = 0; i < 8; ++i) {
        const int b = b0 + 8 * wid + i;
        const float tA = acc[i][0] + bv.x;
        const float tB = acc[i][1] + bv.y;
        float sA, cA, sB, cB;
        __sincosf(tA, &sA, &cA);
        __sincosf(tB, &sB, &cB);
        const float ca = 0.5f * (1.f + cA);   // cos^2(tA/2)
        const float sa = 0.5f * (1.f - cA);   // sin^2(tA/2)
        const float cb = 0.5f * (1.f + cB);
        const float sb = 0.5f * (1.f - cB);
        const float oo = 0.25f * sA * sB;     // sin(tA)/2 * sin(tB)/2

        float* bp = outf + (size_t)b * 32768 + p0 + lane;
        bp[ 0 * 2048] =  ca * cb;
        bp[ 1 * 2048] = 0.f;
        bp[ 2 * 2048] = 0.f;
        bp[ 3 * 2048] = -oo;
        bp[ 4 * 2048] = 0.f;
        bp[ 5 * 2048] =  ca * sb;
        bp[ 6 * 2048] =  oo;
        bp[ 7 * 2048] = 0.f;
        bp[ 8 * 2048] = 0.f;
        bp[ 9 * 2048] =  oo;
        bp[10 * 2048] =  sa * cb;
        bp[11 * 2048] = 0.f;
        bp[12 * 2048] = -oo;
        bp[13 * 2048] = 0.f;
        bp[14 * 2048] = 0.f;
        bp[15 * 2048] =  sa * sb;
    }
}

extern "C" void kernel_launch(void* const* d_in, const int* in_sizes, int n_in,
                              void* d_out, int out_size, void* d_ws, size_t ws_size,
                              hipStream_t stream) {
    const float* X  = (const float*)d_in[0];
    const float* W  = (const float*)d_in[1];
    const float* bv = (const float*)d_in[2];

    // 32 batch-tiles x 32 unit-tiles = 1024 blocks, 256 threads, ~4 blocks/CU
    FeatureEncodingLayer_30374008718005_kernel<<<dim3(1024), dim3(256), 0, stream>>>(
        X, W, bv, (float*)d_out);
}